// Round 1
// baseline (721.082 us; speedup 1.0000x reference)
//
#include <hip/hip_runtime.h>

typedef __bf16 bf16;
typedef bf16 bf16x4_t __attribute__((ext_vector_type(4)));
typedef bf16 bf16x8_t __attribute__((ext_vector_type(8)));
typedef float f32x4_t __attribute__((ext_vector_type(4)));

#define IN_F   256
#define OUT_F  256
#define BOND_F 6
#define KTOT   544      // 256 self | 256 nbr-sum | 6 bond | 26 zero pad
#define KCH    17       // KTOT / 32
#define XSTRIDE 552     // LDS row stride in elements (16B aligned, 2-way bank alias only)

// ---------------------------------------------------------------------------
// Pack W_self (256 rows) + W_deg_d (262 rows) + zero pad into bf16, K-swizzled
// so a B-fragment (8 consecutive k for one column n) is 16B contiguous:
//   Wpk_d[(kq*256 + n)*8 + j] = W[k = kq*8 + j][n]
// ---------------------------------------------------------------------------
__global__ void pack_w_kernel(const float* __restrict__ Ws,
                              const float* __restrict__ W1, const float* __restrict__ W2,
                              const float* __restrict__ W3, const float* __restrict__ W4,
                              const float* __restrict__ W5, bf16* __restrict__ Wpk)
{
    int idx = blockIdx.x * 256 + threadIdx.x;     // 5 * 544 * 256 total
    if (idx >= 5 * KTOT * 256) return;
    int deg  = idx / (KTOT * 256);
    int rem  = idx - deg * (KTOT * 256);
    int kq   = rem >> 11;                         // / (256*8)
    int rem2 = rem & 2047;
    int n    = rem2 >> 3;
    int j    = rem2 & 7;
    int k    = kq * 8 + j;
    const float* Wd = (deg == 0) ? W1 : (deg == 1) ? W2 : (deg == 2) ? W3
                                      : (deg == 3) ? W4 : W5;
    float v = 0.f;
    if (k < 256)      v = Ws[k * 256 + n];
    else if (k < 518) v = Wd[(k - 256) * 256 + n];
    Wpk[idx] = (bf16)v;
}

// ---------------------------------------------------------------------------
// Fused gather + GEMM + bias + ReLU + store + BN-stat kernel, one degree d.
// Block: 256 threads (4 waves). Tile: 64 rows x 256 cols, K=544.
// ---------------------------------------------------------------------------
template<int D>
__global__ __launch_bounds__(256, 2)
void gemm_deg(const float* __restrict__ atomF, const float* __restrict__ bondF,
              const int* __restrict__ an, const int* __restrict__ bnb,
              const bf16* __restrict__ Wpk, const float* __restrict__ bias,
              float* __restrict__ out, float* __restrict__ accum,
              int n_d, int row_off)
{
    __shared__ bf16 Xs[64][XSTRIDE];

    const int tid  = threadIdx.x;
    const int q    = tid >> 6;          // 0..3 (also wave id)
    const int c    = tid & 63;          // col-group (4 cols each)
    const int blk0 = blockIdx.x * 64;

    // ---- Phase 1: build X tile (self | nbr-sum | bond | pad) in LDS ----
    for (int it = 0; it < 16; ++it) {
        const int r  = it * 4 + q;
        const int rl = blk0 + r;
        const int rc = (rl < n_d) ? rl : (n_d - 1);

        const float4 sv = *(const float4*)(atomF + (size_t)(row_off + rc) * IN_F + c * 4);
        float4 nv = make_float4(0.f, 0.f, 0.f, 0.f);
        #pragma unroll
        for (int j = 0; j < D; ++j) {
            const int idx = an[rc * D + j];
            const float4 v = *(const float4*)(atomF + (size_t)idx * IN_F + c * 4);
            nv.x += v.x; nv.y += v.y; nv.z += v.z; nv.w += v.w;
        }
        bf16x4_t s4 = { (bf16)sv.x, (bf16)sv.y, (bf16)sv.z, (bf16)sv.w };
        bf16x4_t n4 = { (bf16)nv.x, (bf16)nv.y, (bf16)nv.z, (bf16)nv.w };
        *(bf16x4_t*)&Xs[r][c * 4]       = s4;
        *(bf16x4_t*)&Xs[r][256 + c * 4] = n4;
    }
    // bond part + zero pad: one thread per row
    if (tid < 64) {
        const int r  = tid;
        const int rl = blk0 + r;
        const int rc = (rl < n_d) ? rl : (n_d - 1);
        float b[BOND_F] = {0.f, 0.f, 0.f, 0.f, 0.f, 0.f};
        #pragma unroll
        for (int j = 0; j < D; ++j) {
            const float* bp = bondF + (size_t)bnb[rc * D + j] * BOND_F;
            const float2 b0 = *(const float2*)(bp + 0);
            const float2 b1 = *(const float2*)(bp + 2);
            const float2 b2 = *(const float2*)(bp + 4);
            b[0] += b0.x; b[1] += b0.y; b[2] += b1.x;
            b[3] += b1.y; b[4] += b2.x; b[5] += b2.y;
        }
        #pragma unroll
        for (int t = 0; t < BOND_F; ++t) Xs[r][512 + t] = (bf16)b[t];
        #pragma unroll
        for (int t = 518; t < KTOT; ++t) Xs[r][t] = (bf16)0.f;
    }
    __syncthreads();

    // ---- Phase 2: MFMA GEMM 64x256 x K=544 ----
    const int w    = q;                 // wave id: cols [64w, 64w+64)
    const int lane = tid & 63;
    const int l15  = lane & 15;
    const int quad = lane >> 4;

    f32x4_t acc[4][4] = {};             // [row-tile][col-tile]

    for (int kc = 0; kc < KCH; ++kc) {
        bf16x8_t a[4], b[4];
        #pragma unroll
        for (int rt = 0; rt < 4; ++rt)
            a[rt] = *(const bf16x8_t*)&Xs[rt * 16 + l15][kc * 32 + quad * 8];
        #pragma unroll
        for (int ct = 0; ct < 4; ++ct) {
            const int n = w * 64 + ct * 16 + l15;
            b[ct] = *(const bf16x8_t*)(Wpk + ((size_t)((kc * 4 + quad) * 256 + n) << 3));
        }
        #pragma unroll
        for (int rt = 0; rt < 4; ++rt)
            #pragma unroll
            for (int ct = 0; ct < 4; ++ct)
                acc[rt][ct] = __builtin_amdgcn_mfma_f32_16x16x32_bf16(
                    a[rt], b[ct], acc[rt][ct], 0, 0, 0);
    }

    // ---- Epilogue: bias + ReLU + store + per-column stats ----
    float csum[4] = {0.f, 0.f, 0.f, 0.f};
    float csq[4]  = {0.f, 0.f, 0.f, 0.f};
    #pragma unroll
    for (int ct = 0; ct < 4; ++ct) {
        const int n = w * 64 + ct * 16 + l15;
        const float bs = bias[n];
        #pragma unroll
        for (int rt = 0; rt < 4; ++rt) {
            #pragma unroll
            for (int rg = 0; rg < 4; ++rg) {
                const int m  = rt * 16 + quad * 4 + rg;
                const int rl = blk0 + m;
                if (rl < n_d) {
                    float v = acc[rt][ct][rg] + bs;
                    v = fmaxf(v, 0.f);
                    out[(size_t)(row_off + rl) * OUT_F + n] = v;
                    csum[ct] += v;
                    csq[ct]  += v * v;
                }
            }
        }
    }
    #pragma unroll
    for (int ct = 0; ct < 4; ++ct) {
        float s  = csum[ct];
        float sq = csq[ct];
        s  += __shfl_xor(s, 16, 64);  s  += __shfl_xor(s, 32, 64);
        sq += __shfl_xor(sq, 16, 64); sq += __shfl_xor(sq, 32, 64);
        if (quad == 0) {
            const int n = w * 64 + ct * 16 + l15;
            atomicAdd(accum + n, s);
            atomicAdd(accum + 256 + n, sq);
        }
    }
}

// ---------------------------------------------------------------------------
// BN finalize: accum[0..255]=col sums, accum[256..511]=col sumsq
// -> ss[0..255]=scale, ss[256..511]=shift
// ---------------------------------------------------------------------------
__global__ void bn_finalize(const float* __restrict__ accum,
                            const float* __restrict__ bnw, const float* __restrict__ bnb,
                            float* __restrict__ ss, int n_rows)
{
    const int t = threadIdx.x;          // 256 threads
    const float inv_n = 1.f / (float)n_rows;
    const float mean  = accum[t] * inv_n;
    const float var   = accum[256 + t] * inv_n - mean * mean;
    const float inv   = rsqrtf(var + 1e-5f);
    const float sc    = bnw[t] * inv;
    ss[t]       = sc;
    ss[256 + t] = bnb[t] - mean * sc;
}

// ---------------------------------------------------------------------------
// BN apply: out = out * scale[col] + shift[col], float4 grid-stride
// ---------------------------------------------------------------------------
__global__ __launch_bounds__(256)
void bn_apply(float* __restrict__ out, const float* __restrict__ ss, size_t n4)
{
    __shared__ float4 s4[64], h4[64];
    if (threadIdx.x < 64) {
        s4[threadIdx.x] = ((const float4*)ss)[threadIdx.x];
        h4[threadIdx.x] = ((const float4*)(ss + 256))[threadIdx.x];
    }
    __syncthreads();
    const size_t stride = (size_t)gridDim.x * blockDim.x;
    for (size_t i = (size_t)blockIdx.x * blockDim.x + threadIdx.x; i < n4; i += stride) {
        float4 v = ((float4*)out)[i];
        const int c = (int)(i & 63);
        const float4 s = s4[c];
        const float4 h = h4[c];
        v.x = v.x * s.x + h.x;
        v.y = v.y * s.y + h.y;
        v.z = v.z * s.z + h.z;
        v.w = v.w * s.w + h.w;
        ((float4*)out)[i] = v;
    }
}

// ---------------------------------------------------------------------------
extern "C" void kernel_launch(void* const* d_in, const int* in_sizes, int n_in,
                              void* d_out, int out_size, void* d_ws, size_t ws_size,
                              hipStream_t stream)
{
    const float* atomF = (const float*)d_in[0];
    const float* bondF = (const float*)d_in[1];
    const int* an[5];
    const int* bnp[5];
    int n_d[5];
    for (int d = 0; d < 5; ++d) {
        an[d]  = (const int*)d_in[2 + 2 * d];
        bnp[d] = (const int*)d_in[3 + 2 * d];
        n_d[d] = in_sizes[2 + 2 * d] / (d + 1);
    }
    const float* Wself = (const float*)d_in[12];
    const float* bias  = (const float*)d_in[13];
    const float* Wd[5] = {(const float*)d_in[14], (const float*)d_in[15],
                          (const float*)d_in[16], (const float*)d_in[17],
                          (const float*)d_in[18]};
    const float* bnw = (const float*)d_in[19];
    const float* bnb = (const float*)d_in[20];
    float* out = (float*)d_out;

    char* ws = (char*)d_ws;
    bf16*  Wpk   = (bf16*)ws;                       // 5*544*256*2 = 1,392,640 B
    float* accum = (float*)(ws + 1392640);          // 512 f32
    float* ss    = (float*)(ws + 1394688);          // 512 f32

    int n_atoms = in_sizes[0] / IN_F;

    hipMemsetAsync(accum, 0, 512 * sizeof(float), stream);

    pack_w_kernel<<<(5 * KTOT * 256 + 255) / 256, 256, 0, stream>>>(
        Wself, Wd[0], Wd[1], Wd[2], Wd[3], Wd[4], Wpk);

    int row_off = 0;
    {
        int g = (n_d[0] + 63) / 64;
        gemm_deg<1><<<g, 256, 0, stream>>>(atomF, bondF, an[0], bnp[0],
            Wpk + 0 * KTOT * 256, bias, out, accum, n_d[0], row_off);
        row_off += n_d[0];
    }
    {
        int g = (n_d[1] + 63) / 64;
        gemm_deg<2><<<g, 256, 0, stream>>>(atomF, bondF, an[1], bnp[1],
            Wpk + 1 * KTOT * 256, bias, out, accum, n_d[1], row_off);
        row_off += n_d[1];
    }
    {
        int g = (n_d[2] + 63) / 64;
        gemm_deg<3><<<g, 256, 0, stream>>>(atomF, bondF, an[2], bnp[2],
            Wpk + 2 * KTOT * 256, bias, out, accum, n_d[2], row_off);
        row_off += n_d[2];
    }
    {
        int g = (n_d[3] + 63) / 64;
        gemm_deg<4><<<g, 256, 0, stream>>>(atomF, bondF, an[3], bnp[3],
            Wpk + 3 * KTOT * 256, bias, out, accum, n_d[3], row_off);
        row_off += n_d[3];
    }
    {
        int g = (n_d[4] + 63) / 64;
        gemm_deg<5><<<g, 256, 0, stream>>>(atomF, bondF, an[4], bnp[4],
            Wpk + 4 * KTOT * 256, bias, out, accum, n_d[4], row_off);
        row_off += n_d[4];
    }

    bn_finalize<<<1, 256, 0, stream>>>(accum, bnw, bnb, ss, n_atoms);

    size_t n4 = (size_t)out_size / 4;
    bn_apply<<<8192, 256, 0, stream>>>(out, ss, n4);
}

// Round 2
// 637.978 us; speedup vs baseline: 1.1303x; 1.1303x over previous
//
#include <hip/hip_runtime.h>

typedef __bf16 bf16;
typedef bf16 bf16x4_t __attribute__((ext_vector_type(4)));
typedef bf16 bf16x8_t __attribute__((ext_vector_type(8)));
typedef float f32x4_t __attribute__((ext_vector_type(4)));

#define IN_F   256
#define OUT_F  256
#define BOND_F 6
#define KTOT   544      // 256 self | 256 nbr-sum | 6 bond | 26 zero pad
#define KCH    17       // KTOT / 32
#define XSTRIDE 552     // LDS row stride in elements (16B aligned)

struct SegArgs {
    const int* an[5];    // segment order: deg5, deg4, deg3, deg2, deg1
    const int* bnb[5];
    const bf16* W[5];    // per-segment packed weight slice
    int n_d[5];
    int row_off[5];
    int blk_end[5];      // cumulative block ends
};

// ---------------------------------------------------------------------------
// Cast atom_features f32 -> bf16 (ws). 8 elems/thread.
// ---------------------------------------------------------------------------
__global__ __launch_bounds__(256)
void cast_atoms(const float* __restrict__ in, bf16* __restrict__ out, int n8)
{
    int i = blockIdx.x * 256 + threadIdx.x;
    if (i >= n8) return;
    const float4 a = ((const float4*)in)[2 * i];
    const float4 b = ((const float4*)in)[2 * i + 1];
    bf16x8_t o = { (bf16)a.x, (bf16)a.y, (bf16)a.z, (bf16)a.w,
                   (bf16)b.x, (bf16)b.y, (bf16)b.z, (bf16)b.w };
    ((bf16x8_t*)out)[i] = o;
}

// ---------------------------------------------------------------------------
// Pack W_self (256 rows) + W_deg_d (262 rows) + zero pad into bf16, K-swizzled:
//   Wpk_d[(kq*256 + n)*8 + j] = W[k = kq*8 + j][n]
// ---------------------------------------------------------------------------
__global__ void pack_w_kernel(const float* __restrict__ Ws,
                              const float* __restrict__ W1, const float* __restrict__ W2,
                              const float* __restrict__ W3, const float* __restrict__ W4,
                              const float* __restrict__ W5, bf16* __restrict__ Wpk)
{
    int idx = blockIdx.x * 256 + threadIdx.x;     // 5 * 544 * 256 total
    if (idx >= 5 * KTOT * 256) return;
    int deg  = idx / (KTOT * 256);
    int rem  = idx - deg * (KTOT * 256);
    int kq   = rem >> 11;
    int rem2 = rem & 2047;
    int n    = rem2 >> 3;
    int j    = rem2 & 7;
    int k    = kq * 8 + j;
    const float* Wd = (deg == 0) ? W1 : (deg == 1) ? W2 : (deg == 2) ? W3
                                      : (deg == 3) ? W4 : W5;
    float v = 0.f;
    if (k < 256)      v = Ws[k * 256 + n];
    else if (k < 518) v = Wd[(k - 256) * 256 + n];
    Wpk[idx] = (bf16)v;
}

// ---------------------------------------------------------------------------
// Fused gather + GEMM + bias + ReLU + store + BN-stat body for one 64-row tile.
// ---------------------------------------------------------------------------
template<int D>
__device__ __forceinline__
void gemm_body(const bf16* __restrict__ atomB, const float* __restrict__ bondF,
               const int* __restrict__ an, const int* __restrict__ bnb,
               const bf16* __restrict__ Wpk, const float* __restrict__ bias,
               float* __restrict__ out, float* __restrict__ accum,
               int n_d, int row_off, int blk_local, bf16 (*Xs)[XSTRIDE])
{
    const int tid  = threadIdx.x;
    const int blk0 = blk_local * 64;

    // ---- Phase 1: build X tile (self | nbr-sum | bond | pad) in LDS ----
    {
        const int rg = tid >> 5;          // 0..7: row within iter-group
        const int c  = tid & 31;          // 8 bf16 elems each

        // preload all gather indices (one latency round-trip)
        int idxs[8][D];
        #pragma unroll
        for (int it = 0; it < 8; ++it) {
            const int rl = blk0 + it * 8 + rg;
            const int rc = (rl < n_d) ? rl : (n_d - 1);
            #pragma unroll
            for (int j = 0; j < D; ++j) idxs[it][j] = an[rc * D + j];
        }

        for (int it = 0; it < 8; ++it) {
            const int r  = it * 8 + rg;
            const int rl = blk0 + r;
            const int rc = (rl < n_d) ? rl : (n_d - 1);
            const bf16x8_t sv = *(const bf16x8_t*)(atomB + (size_t)(row_off + rc) * IN_F + c * 8);
            float nv[8] = {0.f, 0.f, 0.f, 0.f, 0.f, 0.f, 0.f, 0.f};
            #pragma unroll
            for (int j = 0; j < D; ++j) {
                const bf16x8_t v = *(const bf16x8_t*)(atomB + (size_t)idxs[it][j] * IN_F + c * 8);
                #pragma unroll
                for (int t = 0; t < 8; ++t) nv[t] += (float)v[t];
            }
            bf16x8_t n8;
            #pragma unroll
            for (int t = 0; t < 8; ++t) n8[t] = (bf16)nv[t];
            *(bf16x8_t*)&Xs[r][c * 8]       = sv;
            *(bf16x8_t*)&Xs[r][256 + c * 8] = n8;
        }
    }
    // bond part + zero pad: one thread per row
    if (tid < 64) {
        const int r  = tid;
        const int rl = blk0 + r;
        const int rc = (rl < n_d) ? rl : (n_d - 1);
        float b[BOND_F] = {0.f, 0.f, 0.f, 0.f, 0.f, 0.f};
        #pragma unroll
        for (int j = 0; j < D; ++j) {
            const float* bp = bondF + (size_t)bnb[rc * D + j] * BOND_F;
            const float2 b0 = *(const float2*)(bp + 0);
            const float2 b1 = *(const float2*)(bp + 2);
            const float2 b2 = *(const float2*)(bp + 4);
            b[0] += b0.x; b[1] += b0.y; b[2] += b1.x;
            b[3] += b1.y; b[4] += b2.x; b[5] += b2.y;
        }
        #pragma unroll
        for (int t = 0; t < BOND_F; ++t) Xs[r][512 + t] = (bf16)b[t];
        #pragma unroll
        for (int t = 518; t < KTOT; ++t) Xs[r][t] = (bf16)0.f;
    }
    __syncthreads();

    // ---- Phase 2: MFMA GEMM 64x256 x K=544 ----
    const int w    = tid >> 6;          // wave id: cols [64w, 64w+64)
    const int lane = tid & 63;
    const int l15  = lane & 15;
    const int quad = lane >> 4;

    f32x4_t acc[4][4] = {};             // [row-tile][col-tile]

    for (int kc = 0; kc < KCH; ++kc) {
        bf16x8_t a[4], b[4];
        #pragma unroll
        for (int rt = 0; rt < 4; ++rt)
            a[rt] = *(const bf16x8_t*)&Xs[rt * 16 + l15][kc * 32 + quad * 8];
        #pragma unroll
        for (int ct = 0; ct < 4; ++ct) {
            const int n = w * 64 + ct * 16 + l15;
            b[ct] = *(const bf16x8_t*)(Wpk + ((size_t)((kc * 4 + quad) * 256 + n) << 3));
        }
        #pragma unroll
        for (int rt = 0; rt < 4; ++rt)
            #pragma unroll
            for (int ct = 0; ct < 4; ++ct)
                acc[rt][ct] = __builtin_amdgcn_mfma_f32_16x16x32_bf16(
                    a[rt], b[ct], acc[rt][ct], 0, 0, 0);
    }

    // ---- Epilogue: bias + ReLU + store + per-column stats ----
    float csum[4] = {0.f, 0.f, 0.f, 0.f};
    float csq[4]  = {0.f, 0.f, 0.f, 0.f};
    #pragma unroll
    for (int ct = 0; ct < 4; ++ct) {
        const int n = w * 64 + ct * 16 + l15;
        const float bs = bias[n];
        #pragma unroll
        for (int rt = 0; rt < 4; ++rt) {
            #pragma unroll
            for (int rg = 0; rg < 4; ++rg) {
                const int m  = rt * 16 + quad * 4 + rg;
                const int rl = blk0 + m;
                if (rl < n_d) {
                    float v = acc[rt][ct][rg] + bs;
                    v = fmaxf(v, 0.f);
                    out[(size_t)(row_off + rl) * OUT_F + n] = v;
                    csum[ct] += v;
                    csq[ct]  += v * v;
                }
            }
        }
    }
    #pragma unroll
    for (int ct = 0; ct < 4; ++ct) {
        float s  = csum[ct];
        float sq = csq[ct];
        s  += __shfl_xor(s, 16, 64);  s  += __shfl_xor(s, 32, 64);
        sq += __shfl_xor(sq, 16, 64); sq += __shfl_xor(sq, 32, 64);
        if (quad == 0) {
            const int n = w * 64 + ct * 16 + l15;
            atomicAdd(accum + n, s);
            atomicAdd(accum + 256 + n, sq);
        }
    }
}

// ---------------------------------------------------------------------------
// One kernel for all 5 degrees (segment order: deg5 first — heaviest early).
// ---------------------------------------------------------------------------
__global__ __launch_bounds__(256, 2)
void gemm_all(SegArgs S, const bf16* __restrict__ atomB, const float* __restrict__ bondF,
              const float* __restrict__ bias, float* __restrict__ out,
              float* __restrict__ accum)
{
    __shared__ bf16 Xs[64][XSTRIDE];
    const int b = blockIdx.x;
    int s;
    if      (b < S.blk_end[0]) s = 0;
    else if (b < S.blk_end[1]) s = 1;
    else if (b < S.blk_end[2]) s = 2;
    else if (b < S.blk_end[3]) s = 3;
    else                       s = 4;
    const int bl = b - ((s == 0) ? 0 : S.blk_end[s - 1]);
    switch (s) {
    case 0: gemm_body<5>(atomB, bondF, S.an[0], S.bnb[0], S.W[0], bias, out, accum,
                         S.n_d[0], S.row_off[0], bl, Xs); break;
    case 1: gemm_body<4>(atomB, bondF, S.an[1], S.bnb[1], S.W[1], bias, out, accum,
                         S.n_d[1], S.row_off[1], bl, Xs); break;
    case 2: gemm_body<3>(atomB, bondF, S.an[2], S.bnb[2], S.W[2], bias, out, accum,
                         S.n_d[2], S.row_off[2], bl, Xs); break;
    case 3: gemm_body<2>(atomB, bondF, S.an[3], S.bnb[3], S.W[3], bias, out, accum,
                         S.n_d[3], S.row_off[3], bl, Xs); break;
    default: gemm_body<1>(atomB, bondF, S.an[4], S.bnb[4], S.W[4], bias, out, accum,
                          S.n_d[4], S.row_off[4], bl, Xs); break;
    }
}

// ---------------------------------------------------------------------------
__global__ void bn_finalize(const float* __restrict__ accum,
                            const float* __restrict__ bnw, const float* __restrict__ bnb,
                            float* __restrict__ ss, int n_rows)
{
    const int t = threadIdx.x;          // 256 threads
    const float inv_n = 1.f / (float)n_rows;
    const float mean  = accum[t] * inv_n;
    const float var   = accum[256 + t] * inv_n - mean * mean;
    const float inv   = rsqrtf(var + 1e-5f);
    const float sc    = bnw[t] * inv;
    ss[t]       = sc;
    ss[256 + t] = bnb[t] - mean * sc;
}

__global__ __launch_bounds__(256)
void bn_apply(float* __restrict__ out, const float* __restrict__ ss, size_t n4)
{
    __shared__ float4 s4[64], h4[64];
    if (threadIdx.x < 64) {
        s4[threadIdx.x] = ((const float4*)ss)[threadIdx.x];
        h4[threadIdx.x] = ((const float4*)(ss + 256))[threadIdx.x];
    }
    __syncthreads();
    const size_t stride = (size_t)gridDim.x * blockDim.x;
    for (size_t i = (size_t)blockIdx.x * blockDim.x + threadIdx.x; i < n4; i += stride) {
        float4 v = ((float4*)out)[i];
        const int c = (int)(i & 63);
        const float4 s = s4[c];
        const float4 h = h4[c];
        v.x = v.x * s.x + h.x;
        v.y = v.y * s.y + h.y;
        v.z = v.z * s.z + h.z;
        v.w = v.w * s.w + h.w;
        ((float4*)out)[i] = v;
    }
}

// ---------------------------------------------------------------------------
extern "C" void kernel_launch(void* const* d_in, const int* in_sizes, int n_in,
                              void* d_out, int out_size, void* d_ws, size_t ws_size,
                              hipStream_t stream)
{
    const float* atomF = (const float*)d_in[0];
    const float* bondF = (const float*)d_in[1];
    const int* an[5];
    const int* bnp[5];
    int n_d[5];
    for (int d = 0; d < 5; ++d) {
        an[d]  = (const int*)d_in[2 + 2 * d];
        bnp[d] = (const int*)d_in[3 + 2 * d];
        n_d[d] = in_sizes[2 + 2 * d] / (d + 1);
    }
    const float* Wself = (const float*)d_in[12];
    const float* bias  = (const float*)d_in[13];
    const float* Wd[5] = {(const float*)d_in[14], (const float*)d_in[15],
                          (const float*)d_in[16], (const float*)d_in[17],
                          (const float*)d_in[18]};
    const float* bnw = (const float*)d_in[19];
    const float* bnb = (const float*)d_in[20];
    float* out = (float*)d_out;

    char* ws = (char*)d_ws;
    bf16*  Wpk   = (bf16*)ws;                       // 5*544*256*2 = 1,392,640 B
    float* accum = (float*)(ws + 1392640);          // 512 f32
    float* ss    = (float*)(ws + 1394688);          // 512 f32
    bf16*  atomB = (bf16*)(ws + 1396736);           // 200000*256*2 = 102,400,000 B

    const int n_atoms = in_sizes[0] / IN_F;

    hipMemsetAsync(accum, 0, 512 * sizeof(float), stream);

    const int n8 = n_atoms * IN_F / 8;
    cast_atoms<<<(n8 + 255) / 256, 256, 0, stream>>>(atomF, atomB, n8);

    pack_w_kernel<<<(5 * KTOT * 256 + 255) / 256, 256, 0, stream>>>(
        Wself, Wd[0], Wd[1], Wd[2], Wd[3], Wd[4], Wpk);

    // row offsets in reference order (deg1 rows first)
    int row_off_d[5];
    int ro = 0;
    for (int d = 0; d < 5; ++d) { row_off_d[d] = ro; ro += n_d[d]; }

    // segments ordered deg5..deg1 (heaviest blocks dispatched first)
    SegArgs S;
    int cum = 0;
    for (int s = 0; s < 5; ++s) {
        const int d = 4 - s;             // degree index (0-based)
        S.an[s]      = an[d];
        S.bnb[s]     = bnp[d];
        S.W[s]       = Wpk + (size_t)d * KTOT * 256;
        S.n_d[s]     = n_d[d];
        S.row_off[s] = row_off_d[d];
        cum += (n_d[d] + 63) / 64;
        S.blk_end[s] = cum;
    }

    gemm_all<<<cum, 256, 0, stream>>>(S, atomB, bondF, bias, out, accum);

    bn_finalize<<<1, 256, 0, stream>>>(accum, bnw, bnb, ss, n_atoms);

    size_t n4 = (size_t)out_size / 4;
    bn_apply<<<8192, 256, 0, stream>>>(out, ss, n4);
}